// Round 14
// baseline (400.414 us; speedup 1.0000x reference)
//
#include <hip/hip_runtime.h>

// Problem constants
#define S_LEN  2048
#define DMODEL 2048
#define NH     32
#define NKV    8
#define DH     64

typedef _Float16 h8   __attribute__((ext_vector_type(8)));
typedef _Float16 h4   __attribute__((ext_vector_type(4)));
typedef float    f32x4 __attribute__((ext_vector_type(4)));

// ---- async global->LDS, 16B per lane; LDS dest is wave-uniform base + lane*16
__device__ __forceinline__ void load_lds16(const _Float16* g, _Float16* l) {
  typedef const __attribute__((address_space(1))) unsigned int* gp_t;
  typedef __attribute__((address_space(3))) unsigned int* lp_t;
  __builtin_amdgcn_global_load_lds((gp_t)g, (lp_t)l, 16, 0, 0);
}

// ---- fused fp32 -> fp16 convert of all 5 inputs (dst regions adjacent in ws)
#define N8_X  2097152
#define N8_WQ 524288
#define N8_WK 131072
#define N8_WV 131072
#define N8_WO 524288
#define N8_ALL (N8_X + N8_WQ + N8_WK + N8_WV + N8_WO)
__global__ void cvt_all(const float* __restrict__ x, const float* __restrict__ wq,
                        const float* __restrict__ wk, const float* __restrict__ wv,
                        const float* __restrict__ wo, _Float16* __restrict__ dst) {
  int stride = gridDim.x * blockDim.x;
  for (int i = blockIdx.x * blockDim.x + threadIdx.x; i < N8_ALL; i += stride) {
    const float* s;
    int off;
    if (i < N8_X) { s = x; off = i; }
    else if (i < N8_X + N8_WQ) { s = wq; off = i - N8_X; }
    else if (i < N8_X + N8_WQ + N8_WK) { s = wk; off = i - (N8_X + N8_WQ); }
    else if (i < N8_X + N8_WQ + N8_WK + N8_WV) { s = wv; off = i - (N8_X + N8_WQ + N8_WK); }
    else { s = wo; off = i - (N8_X + N8_WQ + N8_WK + N8_WV); }
    float4 a = ((const float4*)s)[2 * off];
    float4 b = ((const float4*)s)[2 * off + 1];
    h8 v = {(_Float16)a.x, (_Float16)a.y, (_Float16)a.z, (_Float16)a.w,
            (_Float16)b.x, (_Float16)b.y, (_Float16)b.z, (_Float16)b.w};
    ((h8*)dst)[i] = v;
  }
}

// ---- RoPE cos/sin table, double-precision reduction (robust to fast-math trig).
__global__ void rope_table_k(float2* __restrict__ tab) {
  int i = blockIdx.x * blockDim.x + threadIdx.x;  // 2048*32 = 65536
  int s = i >> 5, d = i & 31;
  float invf = (float)exp2(-(double)d * 0.4152410118609203);  // log2(10000)/32
  float angf = (float)s * invf;  // match reference's fp32 angle
  double a = (double)angf;
  const double twopi = 6.283185307179586476925287;
  a -= floor(a / twopi) * twopi;
  tab[i] = make_float2((float)cos(a), (float)sin(a));
}

// ---- 128x128-tile GEMM, A[M][2048] f16, Bm[N][2048] f16 (B^T form), fp32 accum.
// r13: 512-thread / 8-wave blocks, wave grid 4x2, per-wave 32x64, acc[2][4].
// r14: (1) TRIPLE-buffered staging with counted vmcnt (T4): stage(t+2) issued
//      at step t -> 2-step prefetch distance; per-step wait vmcnt(2) (only
//      stage(t+1)'s 2 loads outstanding; vmcnt retires in issue order),
//      vmcnt(0) only on the final step. One barrier per step. WAR-safe:
//      passing barrier(t) implies a wave's step t-1 ds_reads completed (MFMA
//      data dep), so DMA into buf (t+2)%3 after the barrier is safe.
//      (2) 4-block XOR swizzle on lA/lB (both-sides, rule #21): physical 16B
//      block p of row r holds logical p^(r&3); cuts the 8-way ds_read bank
//      conflict (rows 64B apart) to 4-way.
// MODE 1: fused Q|K|V proj (Bm = [Wq;Wk;Wv], N=3072). Per 64-col half:
//         base64 <2048: Q -> RoPE -> pre-scaled Q f16 [b][h][s][64]
//         base64 <2560: K -> RoPE -> Kh f16 [b][g][s][64] + Ko f32
//         else:         V -> Vth = V^T f16 [b][g][64][s] + Vo f32 [b][g][s][64]
// MODE 3: out proj -> yF = y [m][2048] f32
template <int MODE>
__global__ __launch_bounds__(512) void gemm128(
    const _Float16* __restrict__ A, const _Float16* __restrict__ Bm,
    _Float16* __restrict__ qH, _Float16* __restrict__ kH, float* __restrict__ kF,
    _Float16* __restrict__ vH, float* __restrict__ vF, float* __restrict__ yF,
    const float2* __restrict__ rtab, const float* __restrict__ tptr) {
  __shared__ __align__(16) _Float16 lA[3][128 * 32];
  __shared__ __align__(16) _Float16 lB[3][128 * 32];
  const int Kd = 2048;
  int t = threadIdx.x;
  int w = t >> 6, lane = t & 63;
  int n0 = blockIdx.x * 128, m0 = blockIdx.y * 128;
  int wr = w >> 1, wc = w & 1;        // 4x2 wave grid: rows wr*32, cols wc*64
  int lq = lane & 15, hi = lane >> 4;

  // staging: wave w covers rows [w*16, w*16+16); lane l -> row +(l>>2).
  // LDS dest is linear (base + l*16B) = physical block l&3 of row l>>2;
  // global SOURCE col block pre-swizzled: (l&3)^((l>>2)&3)  (XOR involution).
  const _Float16* gA = A + (size_t)(m0 + w * 16 + (lane >> 2)) * Kd
                         + (((lane & 3) ^ ((lane >> 2) & 3)) * 8);
  const _Float16* gB = Bm + (size_t)(n0 + w * 16 + (lane >> 2)) * Kd
                          + (((lane & 3) ^ ((lane >> 2) & 3)) * 8);
  int dOff = w * 512;  // f16 elems: (w*16 rows) * 32/row

  f32x4 z4 = {0.f, 0.f, 0.f, 0.f};
  f32x4 acc[2][4];
#pragma unroll
  for (int i = 0; i < 2; i++)
#pragma unroll
    for (int j = 0; j < 4; j++) acc[i][j] = z4;

  // prologue: stage K-steps 0 and 1 into buffers 0 and 1
  load_lds16(gA, &lA[0][dOff]);
  load_lds16(gB, &lB[0][dOff]);
  load_lds16(gA + 32, &lA[1][dOff]);
  load_lds16(gB + 32, &lB[1][dOff]);

  int cur = 0;
  for (int k0 = 0; k0 < Kd; k0 += 32) {
    // wait for stage(t): allow stage(t+1)'s 2 loads to remain outstanding
    if (k0 + 32 < Kd) {
      asm volatile("s_waitcnt vmcnt(2)" ::: "memory");
    } else {
      asm volatile("s_waitcnt vmcnt(0)" ::: "memory");
    }
    __builtin_amdgcn_s_barrier();

    // issue stage(t+2) into the 3rd buffer (its readers were at step t-1,
    // which every wave completed before this barrier)
    if (k0 + 64 < Kd) {
      int nb = cur + 2; if (nb >= 3) nb -= 3;
      load_lds16(gA + k0 + 64, &lA[nb][dOff]);
      load_lds16(gB + k0 + 64, &lB[nb][dOff]);
    }

    // ds_read (swizzled): logical block hi of row r lives at physical block
    // hi^(r&3); r&3 == lq&3 for all fragment rows (bases are multiples of 16)
    h8 af[2], bf[4];
#pragma unroll
    for (int i = 0; i < 2; i++)
      af[i] = *(const h8*)&lA[cur][(wr * 32 + i * 16 + lq) * 32 + ((hi ^ (lq & 3)) * 8)];
#pragma unroll
    for (int j = 0; j < 4; j++)
      bf[j] = *(const h8*)&lB[cur][(wc * 64 + j * 16 + lq) * 32 + ((hi ^ (lq & 3)) * 8)];
#pragma unroll
    for (int i = 0; i < 2; i++)
#pragma unroll
      for (int j = 0; j < 4; j++)
        acc[i][j] = __builtin_amdgcn_mfma_f32_16x16x32_f16(af[i], bf[j], acc[i][j], 0, 0, 0);

    cur = (cur == 2) ? 0 : cur + 1;
  }

  if (MODE == 3) {
#pragma unroll
    for (int ci = 0; ci < 4; ci++) {
      int col = n0 + wc * 64 + ci * 16 + lq;
#pragma unroll
      for (int mi = 0; mi < 2; mi++)
#pragma unroll
        for (int r = 0; r < 4; r++) {
          int m = m0 + wr * 32 + mi * 16 + hi * 4 + r;
          yF[(size_t)m * DMODEL + col] = acc[mi][ci][r];
        }
    }
  } else {  // MODE 1: fused Q|K|V (each 64-col wave half is one head of one output)
    int base64 = n0 + wc * 64;
    if (base64 < 2048) {
      // Q: RoPE + fold softmax scale (incl. log2e for exp2-domain attention)
      float qsc = 0.125f / fmaxf(fabsf(tptr[0]), 1e-6f) * 1.4426950408889634f;
      int head = base64 >> 6;
#pragma unroll
      for (int ci = 0; ci < 2; ci++) {
        int dlo = ci * 16 + lq;
#pragma unroll
        for (int mi = 0; mi < 2; mi++)
#pragma unroll
          for (int r = 0; r < 4; r++) {
            int m = m0 + wr * 32 + mi * 16 + hi * 4 + r;
            int b = m >> 11, s = m & 2047;
            float2 cs = rtab[s * 32 + dlo];
            float lo = acc[mi][ci][r], hv = acc[mi][ci + 2][r];
            float olo = (lo * cs.x - hv * cs.y) * qsc;
            float ohi = (hv * cs.x + lo * cs.y) * qsc;
            size_t base = ((size_t)(b * NH + head) * S_LEN + s) * DH;
            qH[base + dlo] = (_Float16)olo;
            qH[base + dlo + 32] = (_Float16)ohi;
          }
      }
    } else if (base64 < 2560) {
      int head = (base64 - 2048) >> 6;
#pragma unroll
      for (int ci = 0; ci < 2; ci++) {
        int dlo = ci * 16 + lq;
#pragma unroll
        for (int mi = 0; mi < 2; mi++)
#pragma unroll
          for (int r = 0; r < 4; r++) {
            int m = m0 + wr * 32 + mi * 16 + hi * 4 + r;
            int b = m >> 11, s = m & 2047;
            float2 cs = rtab[s * 32 + dlo];
            float lo = acc[mi][ci][r], hv = acc[mi][ci + 2][r];
            float olo = lo * cs.x - hv * cs.y;
            float ohi = hv * cs.x + lo * cs.y;
            size_t bb = ((size_t)(b * NKV + head) * S_LEN + s) * DH;
            kH[bb + dlo] = (_Float16)olo;
            kH[bb + dlo + 32] = (_Float16)ohi;
            kF[bb + dlo] = olo;
            kF[bb + dlo + 32] = ohi;
          }
      }
    } else {
      int head = (base64 - 2560) >> 6;
#pragma unroll
      for (int ci = 0; ci < 4; ci++) {
        int d = ci * 16 + lq;
#pragma unroll
        for (int mi = 0; mi < 2; mi++)
#pragma unroll
          for (int r = 0; r < 4; r++) {
            int m = m0 + wr * 32 + mi * 16 + hi * 4 + r;
            int b = m >> 11, s = m & 2047;
            float v = acc[mi][ci][r];
            vH[((size_t)(b * NKV + head) * DH + d) * S_LEN + s] = (_Float16)v;  // V^T
            vF[((size_t)(b * NKV + head) * S_LEN + s) * DH + d] = v;            // V fp32
          }
      }
    }
  }
}

// ---- causal GQA flash attention. (r11/r12 structure, FROZEN)
// Grid (8,256): xcd=bx pins 16 (b,h) per XCD; chunk = 15-(by>>4) -> longest
// first. Block = 4 waves, wave w owns 32 q-rows. launch_bounds (256,3): the
// ONLY no-spill budget (3x confirmed). K and V staged into block-shared
// double-buffered swizzled LDS via global_load_lds; one vmcnt(0)+s_barrier
// per tile; stage(t+1) issued right after. Swizzle (both-sides, rule #21):
// physical 16B block pb at row r holds logical block pb^(r&7).
__global__ __launch_bounds__(256, 3) void attn_fwd(
    const _Float16* __restrict__ Q, const _Float16* __restrict__ K,
    const _Float16* __restrict__ Vt, _Float16* __restrict__ AO) {
  __shared__ __align__(16) _Float16 lP[4][32 * 72];  // per-wave P[q32][kv64], stride 72
  __shared__ __align__(16) _Float16 lK[2][64 * 64];  // shared K tile, dbuf, swizzled
  __shared__ __align__(16) _Float16 lV[2][64 * 64];  // shared V^T tile, dbuf, swizzled
  int t = threadIdx.x, w = t >> 6, lane = t & 63;
  int lq = lane & 15, hi = lane >> 4;

  int bh = blockIdx.x * 16 + (blockIdx.y & 15);  // 16 consecutive (b,h) per XCD
  int qb = 15 - (blockIdx.y >> 4);               // descending chunk order
  int b = bh >> 5, h = bh & 31, g = h >> 2;

  const _Float16* Qp = Q + ((size_t)(b * NH + h) * S_LEN) * DH;
  const _Float16* Kp = K + ((size_t)(b * NKV + g) * S_LEN) * DH;
  const _Float16* Vp = Vt + ((size_t)(b * NKV + g) * DH) * S_LEN;

  f32x4 z4 = {0.f, 0.f, 0.f, 0.f};
  int q0 = qb * 128 + w * 32;

  // staging addresses: wave w covers rows [w*16, w*16+16) of the 64-row tile,
  // lane l -> row +(l>>3), physical block l&7 <- logical block (l&7)^(l>>3).
  int swz = ((lane & 7) ^ (lane >> 3)) * 8;
  size_t sko0 = (size_t)(w * 16 + (lane >> 3)) * DH + (size_t)swz;      // K (row stride 64)
  size_t svo0 = (size_t)(w * 16 + (lane >> 3)) * S_LEN + (size_t)swz;   // V^T (row stride 2048)

  // Q fragments in registers (B-operand of QK^T), pre-scaled
  h8 qf[2][2];
#pragma unroll
  for (int cf = 0; cf < 2; cf++)
#pragma unroll
    for (int dc = 0; dc < 2; dc++)
      qf[cf][dc] = *(const h8*)&Qp[(size_t)(q0 + lq + 16 * cf) * DH + dc * 32 + hi * 8];

  f32x4 ot[4][2];  // O^T: [dv 4x16][q 2x16]
#pragma unroll
  for (int rf = 0; rf < 4; rf++)
#pragma unroll
    for (int cf = 0; cf < 2; cf++) ot[rf][cf] = z4;
  float mrun[2] = {-3e38f, -3e38f};
  float lrun[2] = {0.f, 0.f};

  int NT = 2 * qb + 2;  // uniform tile count for all waves (barrier lockstep)

  // prologue: stage K(0), V(0) into buffer 0
  load_lds16(Kp + sko0, &lK[0][(w * 16) * 64]);
  load_lds16(Kp + sko0 + (size_t)8 * DH, &lK[0][(w * 16 + 8) * 64]);
  load_lds16(Vp + svo0, &lV[0][(w * 16) * 64]);
  load_lds16(Vp + svo0 + (size_t)8 * S_LEN, &lV[0][(w * 16 + 8) * 64]);

  for (int tk = 0; tk < NT; tk++) {
    int kv0 = tk * 64;

    // staged K(tk)/V(tk) landed (own-wave vmem drain) + block-wide sync
    asm volatile("s_waitcnt vmcnt(0)" ::: "memory");
    __builtin_amdgcn_s_barrier();

    // issue stage of K(tk+1)/V(tk+1) into the other buffer (its previous
    // readers finished before this barrier). Lands during this whole tile;
    // drained by next loop-top vmcnt(0). Block-uniform guard.
    if (tk + 1 < NT) {
      _Float16* nK = &lK[(tk + 1) & 1][0];
      _Float16* nV = &lV[(tk + 1) & 1][0];
      size_t kvn = (size_t)(kv0 + 64);
      load_lds16(Kp + kvn * DH + sko0, nK + (w * 16) * 64);
      load_lds16(Kp + kvn * DH + sko0 + (size_t)8 * DH, nK + (w * 16 + 8) * 64);
      load_lds16(Vp + svo0 + kvn, nV + (w * 16) * 64);
      load_lds16(Vp + svo0 + kvn + (size_t)8 * S_LEN, nV + (w * 16 + 8) * 64);
    }

    // S^T = K Q^T (contraction over d); K from shared swizzled LDS.
    f32x4 sc[4][2];
#pragma unroll
    for (int rf = 0; rf < 4; rf++)
#pragma unroll
      for (int cf = 0; cf < 2; cf++) sc[rf][cf] = z4;
    {
      const _Float16* kb = &lK[tk & 1][0];
#pragma unroll
      for (int dc = 0; dc < 2; dc++) {
        h8 kf[4];
#pragma unroll
        for (int rf = 0; rf < 4; rf++)
          kf[rf] = *(const h8*)&kb[(rf * 16 + lq) * 64 + (((dc * 4 + hi) ^ (lq & 7)) * 8)];
#pragma unroll
        for (int rf = 0; rf < 4; rf++)
#pragma unroll
          for (int cf = 0; cf < 2; cf++)
            sc[rf][cf] = __builtin_amdgcn_mfma_f32_16x16x32_f16(kf[rf], qf[cf][dc], sc[rf][cf], 0, 0, 0);
      }
    }

    // causal mask (diag tiles only; no scale pass needed)
    if (kv0 + 63 > q0) {
#pragma unroll
      for (int rf = 0; rf < 4; rf++)
#pragma unroll
        for (int cf = 0; cf < 2; cf++)
#pragma unroll
          for (int r = 0; r < 4; r++) {
            int kv = kv0 + rf * 16 + hi * 4 + r;
            int q = q0 + lq + 16 * cf;
            if (kv > q) sc[rf][cf][r] = -1e30f;
          }
    }

    // row max (per q): 16 in-lane + 2 shuffles
    float mt[2];
#pragma unroll
    for (int cf = 0; cf < 2; cf++) {
      float m2 = -3e38f;
#pragma unroll
      for (int rf = 0; rf < 4; rf++)
#pragma unroll
        for (int r = 0; r < 4; r++) m2 = fmaxf(m2, sc[rf][cf][r]);
      m2 = fmaxf(m2, __shfl_xor(m2, 16));
      m2 = fmaxf(m2, __shfl_xor(m2, 32));
      mt[cf] = m2;
    }

    // defer-max (T13): only rescale when the max moved by > 8 (log2 units)
    bool need = !__all((mt[0] - mrun[0] <= 8.f) && (mt[1] - mrun[1] <= 8.f));
    if (need) {
#pragma unroll
      for (int cf = 0; cf < 2; cf++) {
        float mnew = fmaxf(mrun[cf], mt[cf]);
        float al = __builtin_amdgcn_exp2f(mrun[cf] - mnew);
        mrun[cf] = mnew;
        lrun[cf] *= al;
#pragma unroll
        for (int rf = 0; rf < 4; rf++)
#pragma unroll
          for (int r = 0; r < 4; r++) ot[rf][cf][r] *= al;
      }
    }

    // P = exp2(S - m), row sums
    float ls[2] = {0.f, 0.f};
#pragma unroll
    for (int rf = 0; rf < 4; rf++)
#pragma unroll
      for (int cf = 0; cf < 2; cf++)
#pragma unroll
        for (int r = 0; r < 4; r++) {
          float p = __builtin_amdgcn_exp2f(sc[rf][cf][r] - mrun[cf]);
          sc[rf][cf][r] = p;
          ls[cf] += p;
        }
#pragma unroll
    for (int cf = 0; cf < 2; cf++) {
      float s2 = ls[cf];
      s2 += __shfl_xor(s2, 16);
      s2 += __shfl_xor(s2, 32);
      lrun[cf] += s2;
    }

    // pack P -> wave-private LDS [q][kv]
#pragma unroll
    for (int rf = 0; rf < 4; rf++)
#pragma unroll
      for (int cf = 0; cf < 2; cf++) {
        h4 p4;
#pragma unroll
        for (int r = 0; r < 4; r++) p4[r] = (_Float16)sc[rf][cf][r];
        *(h4*)&lP[w][(lq + 16 * cf) * 72 + rf * 16 + hi * 4] = p4;
      }
    asm volatile("s_waitcnt lgkmcnt(0)" ::: "memory");
    __builtin_amdgcn_sched_barrier(0);

    // O^T += V^T P^T (contraction over kv). V from shared swizzled LDS.
    {
      const _Float16* vb = &lV[tk & 1][0];
#pragma unroll
      for (int kvc = 0; kvc < 2; kvc++) {
        h8 vf[4];
#pragma unroll
        for (int rf = 0; rf < 4; rf++)
          vf[rf] = *(const h8*)&vb[(rf * 16 + lq) * 64 + (((kvc * 4 + hi) ^ (lq & 7)) * 8)];
        h8 pb[2];
#pragma unroll
        for (int cf = 0; cf < 2; cf++)
          pb[cf] = *(const h8*)&lP[w][(lq + 16 * cf) * 72 + kvc * 32 + hi * 8];
#pragma unroll
        for (int rf = 0; rf < 4; rf++)
#pragma unroll
          for (int cf = 0; cf < 2; cf++)
            ot[rf][cf] = __builtin_amdgcn_mfma_f32_16x16x32_f16(vf[rf], pb[cf], ot[rf][cf], 0, 0, 0);
      }
    }
    // no end-of-tile barrier: ds_read data already consumed by MFMAs above;
    // next loop-top vmcnt(0)+s_barrier orders buffer reuse.
  }

  // normalize + store to AO[b*S+q][h*64+dv] f16 (input of out-proj GEMM)
#pragma unroll
  for (int cf = 0; cf < 2; cf++) {
    float inv = 1.0f / lrun[cf];
    size_t row = (size_t)b * S_LEN + q0 + lq + 16 * cf;
#pragma unroll
    for (int rf = 0; rf < 4; rf++) {
      h4 o;
#pragma unroll
      for (int r = 0; r < 4; r++) o[r] = (_Float16)(ot[rf][cf][r] * inv);
      *(h4*)&AO[row * DMODEL + h * DH + rf * 16 + hi * 4] = o;
    }
  }
}

extern "C" void kernel_launch(void* const* d_in, const int* in_sizes, int n_in,
                              void* d_out, int out_size, void* d_ws, size_t ws_size,
                              hipStream_t stream) {
  const float* x  = (const float*)d_in[0];
  const float* Wq = (const float*)d_in[1];
  const float* Wk = (const float*)d_in[2];
  const float* Wv = (const float*)d_in[3];
  const float* Wo = (const float*)d_in[4];
  const float* tp = (const float*)d_in[5];

  float* y  = (float*)d_out;                 // 16,777,216 f32
  float* Ko = y + (size_t)16777216;          //  4,194,304 (post-RoPE K fp32)
  float* Vo = Ko + (size_t)4194304;          //  4,194,304 (V fp32)

  // workspace carve (fp16 elems) — total 68.5 MB. xh..woh adjacent => single cvt;
  // wqh/wkh/wvh adjacent => ONE fused QKV GEMM (N=3072; 2048/2560 are 128-aligned).
  _Float16* xh  = (_Float16*)d_ws;           // 16,777,216
  _Float16* wqh = xh + 16777216;             //  4,194,304
  _Float16* wkh = wqh + 4194304;             //  1,048,576
  _Float16* wvh = wkh + 1048576;             //  1,048,576
  _Float16* woh = wvh + 1048576;             //  4,194,304
  _Float16* Kh  = woh + 4194304;             //  4,194,304  [b][g][s][64]
  _Float16* Vth = Kh + 4194304;              //  4,194,304  [b][g][64][s]
  float2*   rtab = (float2*)(Vth + 4194304); //    524,288 B
  _Float16* AOh = xh;                        // alias: x dead after QKV GEMM
  _Float16* Qh  = (_Float16*)d_out;          // alias: first 32MB of y; y written last
  (void)wkh; (void)wvh;

  cvt_all<<<2048, 256, 0, stream>>>(x, Wq, Wk, Wv, Wo, xh);
  rope_table_k<<<256, 256, 0, stream>>>(rtab);

  gemm128<1><<<dim3(24, 64), 512, 0, stream>>>(xh, wqh, Qh, Kh, Ko, Vth, Vo, nullptr, rtab, tp);
  attn_fwd<<<dim3(8, 256), 256, 0, stream>>>(Qh, Kh, Vth, AOh);
  gemm128<3><<<dim3(16, 64), 512, 0, stream>>>(AOh, woh, nullptr, nullptr, nullptr, nullptr, nullptr, y, rtab, tp);
}

// Round 15
// 367.413 us; speedup vs baseline: 1.0898x; 1.0898x over previous
//
#include <hip/hip_runtime.h>

// Problem constants
#define S_LEN  2048
#define DMODEL 2048
#define NH     32
#define NKV    8
#define DH     64

typedef _Float16 h8   __attribute__((ext_vector_type(8)));
typedef _Float16 h4   __attribute__((ext_vector_type(4)));
typedef float    f32x4 __attribute__((ext_vector_type(4)));

// ---- async global->LDS, 16B per lane; LDS dest is wave-uniform base + lane*16
__device__ __forceinline__ void load_lds16(const _Float16* g, _Float16* l) {
  typedef const __attribute__((address_space(1))) unsigned int* gp_t;
  typedef __attribute__((address_space(3))) unsigned int* lp_t;
  __builtin_amdgcn_global_load_lds((gp_t)g, (lp_t)l, 16, 0, 0);
}

// ---- fused fp32 -> fp16 convert of all 5 inputs (dst regions adjacent in ws)
#define N8_X  2097152
#define N8_WQ 524288
#define N8_WK 131072
#define N8_WV 131072
#define N8_WO 524288
#define N8_ALL (N8_X + N8_WQ + N8_WK + N8_WV + N8_WO)
__global__ void cvt_all(const float* __restrict__ x, const float* __restrict__ wq,
                        const float* __restrict__ wk, const float* __restrict__ wv,
                        const float* __restrict__ wo, _Float16* __restrict__ dst) {
  int stride = gridDim.x * blockDim.x;
  for (int i = blockIdx.x * blockDim.x + threadIdx.x; i < N8_ALL; i += stride) {
    const float* s;
    int off;
    if (i < N8_X) { s = x; off = i; }
    else if (i < N8_X + N8_WQ) { s = wq; off = i - N8_X; }
    else if (i < N8_X + N8_WQ + N8_WK) { s = wk; off = i - (N8_X + N8_WQ); }
    else if (i < N8_X + N8_WQ + N8_WK + N8_WV) { s = wv; off = i - (N8_X + N8_WQ + N8_WK); }
    else { s = wo; off = i - (N8_X + N8_WQ + N8_WK + N8_WV); }
    float4 a = ((const float4*)s)[2 * off];
    float4 b = ((const float4*)s)[2 * off + 1];
    h8 v = {(_Float16)a.x, (_Float16)a.y, (_Float16)a.z, (_Float16)a.w,
            (_Float16)b.x, (_Float16)b.y, (_Float16)b.z, (_Float16)b.w};
    ((h8*)dst)[i] = v;
  }
}

// ---- RoPE cos/sin table, double-precision reduction (robust to fast-math trig).
__global__ void rope_table_k(float2* __restrict__ tab) {
  int i = blockIdx.x * blockDim.x + threadIdx.x;  // 2048*32 = 65536
  int s = i >> 5, d = i & 31;
  float invf = (float)exp2(-(double)d * 0.4152410118609203);  // log2(10000)/32
  float angf = (float)s * invf;  // match reference's fp32 angle
  double a = (double)angf;
  const double twopi = 6.283185307179586476925287;
  a -= floor(a / twopi) * twopi;
  tab[i] = make_float2((float)cos(a), (float)sin(a));
}

// ---- 256x256-tile GEMM, BK=64, 512 threads / 8 waves (2M x 4N), per-wave
// output 128x64, acc[8][4]. Rationale (r15): the 128-tile kernels were
// LDS-READ-VOLUME bound (each staged byte re-read by 2-4 waves; ~40% MfmaUtil
// ceiling at 256B/cy/CU). Per-wave 128x64 halves LDS bytes/MFMA.
// Schedule: counted-vmcnt pipeline (T4) that NEVER drains in-loop:
//   per wave, per tile: 4 B-loads then 4 A-loads (order matters for vmcnt).
//   iter t: vmcnt(4)+barrier  -> B(t) visible   [barrier also fences buffer
//           reuse: stage(t+1) into nxt only after ALL waves finished t-1]
//           issue stage(t+1); read B-frags (8 ds_read, cached whole tile);
//           vmcnt(8) [t+1's 8 loads stay in flight] + barrier -> A(t) visible
//           4 phases x {4 A ds_read; setprio(1); 16 MFMA; setprio(0)}  (T5)
// LDS swizzle (G4-verified, rows = 64 f16 = 128B): 16B block bb of row r
// stored at bb^(r&7) -> 2-way conflict (free). Both-sides (rule #21):
// linear DMA dest + pre-swizzled global source + swizzled ds_read.
// MODE 1: fused Q|K|V proj (Bm = [Wq;Wk;Wv], N=3072). Per 64-col wave chunk:
//         <2048: Q->RoPE->pre-scaled Q f16; <2560: K->RoPE->Kh f16+Ko f32;
//         else: V -> Vth=V^T f16 + Vo f32.
// MODE 3: out proj -> yF = y [m][2048] f32
template <int MODE>
__global__ __launch_bounds__(512, 2) void gemm256(
    const _Float16* __restrict__ A, const _Float16* __restrict__ Bm,
    _Float16* __restrict__ qH, _Float16* __restrict__ kH, float* __restrict__ kF,
    _Float16* __restrict__ vH, float* __restrict__ vF, float* __restrict__ yF,
    const float2* __restrict__ rtab, const float* __restrict__ tptr) {
  __shared__ __align__(16) _Float16 lA[2][256 * 64];
  __shared__ __align__(16) _Float16 lB[2][256 * 64];
  const int Kd = 2048;
  int t = threadIdx.x;
  int w = t >> 6, lane = t & 63;
  int n0 = blockIdx.x * 256, m0 = blockIdx.y * 256;
  int wr = w >> 2, wc = w & 3;   // 2M x 4N wave grid: rows wr*128, cols wc*64
  int lq = lane & 15, hi = lane >> 4;

  // staging: wave w covers rows [w*32, w*32+32) of the 256-row tile, in 4
  // loads of 8 rows. Lane l -> row +(l>>3), phys block l&7 <- logical
  // (l&7)^(l>>3)  (rows within a load are congruent mod 8).
  int swz = ((lane & 7) ^ (lane >> 3)) * 8;
  const _Float16* pA = A + (size_t)(m0 + w * 32 + (lane >> 3)) * Kd + swz;
  const _Float16* pB = Bm + (size_t)(n0 + w * 32 + (lane >> 3)) * Kd + swz;
  int dRow = (w * 32) * 64;  // wave's LDS dest base (f16 elems)

  f32x4 z4 = {0.f, 0.f, 0.f, 0.f};
  f32x4 acc[8][4];
#pragma unroll
  for (int i = 0; i < 8; i++)
#pragma unroll
    for (int j = 0; j < 4; j++) acc[i][j] = z4;

  // prologue: stage tile 0 into buffer 0 (B first, then A — vmcnt order)
#pragma unroll
  for (int i = 0; i < 4; i++)
    load_lds16(pB + (size_t)(i * 8) * Kd, &lB[0][dRow + i * 8 * 64]);
#pragma unroll
  for (int i = 0; i < 4; i++)
    load_lds16(pA + (size_t)(i * 8) * Kd, &lA[0][dRow + i * 8 * 64]);

  const int NT = Kd / 64;  // 32
  for (int tt = 0; tt < NT; tt++) {
    int cur = tt & 1, nxt = cur ^ 1;

    // B(tt) landed per-wave (oldest 4 of our 8 outstanding) + block sync.
    // This barrier also guarantees every wave finished iteration tt-1's
    // ds_reads of buffer nxt -> safe to DMA into nxt below.
    asm volatile("s_waitcnt vmcnt(4)" ::: "memory");
    __builtin_amdgcn_s_barrier();

    if (tt + 1 < NT) {
      int k0n = (tt + 1) * 64;
#pragma unroll
      for (int i = 0; i < 4; i++)
        load_lds16(pB + (size_t)(i * 8) * Kd + k0n, &lB[nxt][dRow + i * 8 * 64]);
#pragma unroll
      for (int i = 0; i < 4; i++)
        load_lds16(pA + (size_t)(i * 8) * Kd + k0n, &lA[nxt][dRow + i * 8 * 64]);
    }

    // B fragments for the whole tile (cached in regs): rows wc*64 + j*16 + lq,
    // logical block s*4+hi at phys (s*4+hi)^(lq&7).
    h8 bf[4][2];
#pragma unroll
    for (int j = 0; j < 4; j++)
#pragma unroll
      for (int s = 0; s < 2; s++)
        bf[j][s] = *(const h8*)&lB[cur][(wc * 64 + j * 16 + lq) * 64 + (((s * 4 + hi) ^ (lq & 7)) * 8)];

    // A(tt) landed (retire our 4 A-loads; tile tt+1's 8 stay in flight)
    if (tt + 1 < NT) {
      asm volatile("s_waitcnt vmcnt(8)" ::: "memory");
    } else {
      asm volatile("s_waitcnt vmcnt(0)" ::: "memory");
    }
    __builtin_amdgcn_s_barrier();

    // 4 phases: rows {2p, 2p+1} x 4 cols x 2 ksubs = 16 MFMA each
#pragma unroll
    for (int p = 0; p < 4; p++) {
      h8 af[2][2];
#pragma unroll
      for (int di = 0; di < 2; di++)
#pragma unroll
        for (int s = 0; s < 2; s++)
          af[di][s] = *(const h8*)&lA[cur][(wr * 128 + (p * 2 + di) * 16 + lq) * 64 + (((s * 4 + hi) ^ (lq & 7)) * 8)];
      __builtin_amdgcn_s_setprio(1);
#pragma unroll
      for (int s = 0; s < 2; s++)
#pragma unroll
        for (int di = 0; di < 2; di++)
#pragma unroll
          for (int j = 0; j < 4; j++)
            acc[p * 2 + di][j] = __builtin_amdgcn_mfma_f32_16x16x32_f16(af[di][s], bf[j][s], acc[p * 2 + di][j], 0, 0, 0);
      __builtin_amdgcn_s_setprio(0);
    }
  }

  if (MODE == 3) {
#pragma unroll
    for (int ci = 0; ci < 4; ci++) {
      int col = n0 + wc * 64 + ci * 16 + lq;
#pragma unroll
      for (int i = 0; i < 8; i++)
#pragma unroll
        for (int r = 0; r < 4; r++) {
          int m = m0 + wr * 128 + i * 16 + hi * 4 + r;
          yF[(size_t)m * DMODEL + col] = acc[i][ci][r];
        }
    }
  } else {  // MODE 1: fused Q|K|V (each 64-col wave chunk is one head of one output)
    int base64 = n0 + wc * 64;
    if (base64 < 2048) {
      // Q: RoPE + fold softmax scale (incl. log2e for exp2-domain attention)
      float qsc = 0.125f / fmaxf(fabsf(tptr[0]), 1e-6f) * 1.4426950408889634f;
      int head = base64 >> 6;
#pragma unroll
      for (int ci = 0; ci < 2; ci++) {
        int dlo = ci * 16 + lq;
#pragma unroll
        for (int i = 0; i < 8; i++)
#pragma unroll
          for (int r = 0; r < 4; r++) {
            int m = m0 + wr * 128 + i * 16 + hi * 4 + r;
            int b = m >> 11, s = m & 2047;
            float2 cs = rtab[s * 32 + dlo];
            float lo = acc[i][ci][r], hv = acc[i][ci + 2][r];
            float olo = (lo * cs.x - hv * cs.y) * qsc;
            float ohi = (hv * cs.x + lo * cs.y) * qsc;
            size_t base = ((size_t)(b * NH + head) * S_LEN + s) * DH;
            qH[base + dlo] = (_Float16)olo;
            qH[base + dlo + 32] = (_Float16)ohi;
          }
      }
    } else if (base64 < 2560) {
      int head = (base64 - 2048) >> 6;
#pragma unroll
      for (int ci = 0; ci < 2; ci++) {
        int dlo = ci * 16 + lq;
#pragma unroll
        for (int i = 0; i < 8; i++)
#pragma unroll
          for (int r = 0; r < 4; r++) {
            int m = m0 + wr * 128 + i * 16 + hi * 4 + r;
            int b = m >> 11, s = m & 2047;
            float2 cs = rtab[s * 32 + dlo];
            float lo = acc[i][ci][r], hv = acc[i][ci + 2][r];
            float olo = lo * cs.x - hv * cs.y;
            float ohi = hv * cs.x + lo * cs.y;
            size_t bb = ((size_t)(b * NKV + head) * S_LEN + s) * DH;
            kH[bb + dlo] = (_Float16)olo;
            kH[bb + dlo + 32] = (_Float16)ohi;
            kF[bb + dlo] = olo;
            kF[bb + dlo + 32] = ohi;
          }
      }
    } else {
      int head = (base64 - 2560) >> 6;
#pragma unroll
      for (int ci = 0; ci < 4; ci++) {
        int d = ci * 16 + lq;
#pragma unroll
        for (int i = 0; i < 8; i++)
#pragma unroll
          for (int r = 0; r < 4; r++) {
            int m = m0 + wr * 128 + i * 16 + hi * 4 + r;
            int b = m >> 11, s = m & 2047;
            float v = acc[i][ci][r];
            vH[((size_t)(b * NKV + head) * DH + d) * S_LEN + s] = (_Float16)v;  // V^T
            vF[((size_t)(b * NKV + head) * S_LEN + s) * DH + d] = v;            // V fp32
          }
      }
    }
  }
}

// ---- causal GQA flash attention. (r11 structure, FROZEN)
// Grid (8,256): xcd=bx pins 16 (b,h) per XCD; chunk = 15-(by>>4) -> longest
// first. Block = 4 waves, wave w owns 32 q-rows. launch_bounds (256,3): the
// ONLY no-spill budget (3x confirmed). K and V staged into block-shared
// double-buffered swizzled LDS via global_load_lds; one vmcnt(0)+s_barrier
// per tile; stage(t+1) issued right after. Swizzle (both-sides, rule #21):
// physical 16B block pb at row r holds logical block pb^(r&7).
__global__ __launch_bounds__(256, 3) void attn_fwd(
    const _Float16* __restrict__ Q, const _Float16* __restrict__ K,
    const _Float16* __restrict__ Vt, _Float16* __restrict__ AO) {
  __shared__ __align__(16) _Float16 lP[4][32 * 72];  // per-wave P[q32][kv64], stride 72
  __shared__ __align__(16) _Float16 lK[2][64 * 64];  // shared K tile, dbuf, swizzled
  __shared__ __align__(16) _Float16 lV[2][64 * 64];  // shared V^T tile, dbuf, swizzled
  int t = threadIdx.x, w = t >> 6, lane = t & 63;
  int lq = lane & 15, hi = lane >> 4;

  int bh = blockIdx.x * 16 + (blockIdx.y & 15);  // 16 consecutive (b,h) per XCD
  int qb = 15 - (blockIdx.y >> 4);               // descending chunk order
  int b = bh >> 5, h = bh & 31, g = h >> 2;

  const _Float16* Qp = Q + ((size_t)(b * NH + h) * S_LEN) * DH;
  const _Float16* Kp = K + ((size_t)(b * NKV + g) * S_LEN) * DH;
  const _Float16* Vp = Vt + ((size_t)(b * NKV + g) * DH) * S_LEN;

  f32x4 z4 = {0.f, 0.f, 0.f, 0.f};
  int q0 = qb * 128 + w * 32;

  int swz = ((lane & 7) ^ (lane >> 3)) * 8;
  size_t sko0 = (size_t)(w * 16 + (lane >> 3)) * DH + (size_t)swz;      // K (row stride 64)
  size_t svo0 = (size_t)(w * 16 + (lane >> 3)) * S_LEN + (size_t)swz;   // V^T (row stride 2048)

  // Q fragments in registers (B-operand of QK^T), pre-scaled
  h8 qf[2][2];
#pragma unroll
  for (int cf = 0; cf < 2; cf++)
#pragma unroll
    for (int dc = 0; dc < 2; dc++)
      qf[cf][dc] = *(const h8*)&Qp[(size_t)(q0 + lq + 16 * cf) * DH + dc * 32 + hi * 8];

  f32x4 ot[4][2];  // O^T: [dv 4x16][q 2x16]
#pragma unroll
  for (int rf = 0; rf < 4; rf++)
#pragma unroll
    for (int cf = 0; cf < 2; cf++) ot[rf][cf] = z4;
  float mrun[2] = {-3e38f, -3e38f};
  float lrun[2] = {0.f, 0.f};

  int NT = 2 * qb + 2;  // uniform tile count for all waves (barrier lockstep)

  // prologue: stage K(0), V(0) into buffer 0
  load_lds16(Kp + sko0, &lK[0][(w * 16) * 64]);
  load_lds16(Kp + sko0 + (size_t)8 * DH, &lK[0][(w * 16 + 8) * 64]);
  load_lds16(Vp + svo0, &lV[0][(w * 16) * 64]);
  load_lds16(Vp + svo0 + (size_t)8 * S_LEN, &lV[0][(w * 16 + 8) * 64]);

  for (int tk = 0; tk < NT; tk++) {
    int kv0 = tk * 64;

    asm volatile("s_waitcnt vmcnt(0)" ::: "memory");
    __builtin_amdgcn_s_barrier();

    if (tk + 1 < NT) {
      _Float16* nK = &lK[(tk + 1) & 1][0];
      _Float16* nV = &lV[(tk + 1) & 1][0];
      size_t kvn = (size_t)(kv0 + 64);
      load_lds16(Kp + kvn * DH + sko0, nK + (w * 16) * 64);
      load_lds16(Kp + kvn * DH + sko0 + (size_t)8 * DH, nK + (w * 16 + 8) * 64);
      load_lds16(Vp + svo0 + kvn, nV + (w * 16) * 64);
      load_lds16(Vp + svo0 + kvn + (size_t)8 * S_LEN, nV + (w * 16 + 8) * 64);
    }

    // S^T = K Q^T (contraction over d); K from shared swizzled LDS.
    f32x4 sc[4][2];
#pragma unroll
    for (int rf = 0; rf < 4; rf++)
#pragma unroll
      for (int cf = 0; cf < 2; cf++) sc[rf][cf] = z4;
    {
      const _Float16* kb = &lK[tk & 1][0];
#pragma unroll
      for (int dc = 0; dc < 2; dc++) {
        h8 kf[4];
#pragma unroll
        for (int rf = 0; rf < 4; rf++)
          kf[rf] = *(const h8*)&kb[(rf * 16 + lq) * 64 + (((dc * 4 + hi) ^ (lq & 7)) * 8)];
#pragma unroll
        for (int rf = 0; rf < 4; rf++)
#pragma unroll
          for (int cf = 0; cf < 2; cf++)
            sc[rf][cf] = __builtin_amdgcn_mfma_f32_16x16x32_f16(kf[rf], qf[cf][dc], sc[rf][cf], 0, 0, 0);
      }
    }

    // causal mask (diag tiles only)
    if (kv0 + 63 > q0) {
#pragma unroll
      for (int rf = 0; rf < 4; rf++)
#pragma unroll
        for (int cf = 0; cf < 2; cf++)
#pragma unroll
          for (int r = 0; r < 4; r++) {
            int kv = kv0 + rf * 16 + hi * 4 + r;
            int q = q0 + lq + 16 * cf;
            if (kv > q) sc[rf][cf][r] = -1e30f;
          }
    }

    // row max (per q): 16 in-lane + 2 shuffles
    float mt[2];
#pragma unroll
    for (int cf = 0; cf < 2; cf++) {
      float m2 = -3e38f;
#pragma unroll
      for (int rf = 0; rf < 4; rf++)
#pragma unroll
        for (int r = 0; r < 4; r++) m2 = fmaxf(m2, sc[rf][cf][r]);
      m2 = fmaxf(m2, __shfl_xor(m2, 16));
      m2 = fmaxf(m2, __shfl_xor(m2, 32));
      mt[cf] = m2;
    }

    // defer-max (T13)
    bool need = !__all((mt[0] - mrun[0] <= 8.f) && (mt[1] - mrun[1] <= 8.f));
    if (need) {
#pragma unroll
      for (int cf = 0; cf < 2; cf++) {
        float mnew = fmaxf(mrun[cf], mt[cf]);
        float al = __builtin_amdgcn_exp2f(mrun[cf] - mnew);
        mrun[cf] = mnew;
        lrun[cf] *= al;
#pragma unroll
        for (int rf = 0; rf < 4; rf++)
#pragma unroll
          for (int r = 0; r < 4; r++) ot[rf][cf][r] *= al;
      }
    }

    // P = exp2(S - m), row sums
    float ls[2] = {0.f, 0.f};
#pragma unroll
    for (int rf = 0; rf < 4; rf++)
#pragma unroll
      for (int cf = 0; cf < 2; cf++)
#pragma unroll
        for (int r = 0; r < 4; r++) {
          float p = __builtin_amdgcn_exp2f(sc[rf][cf][r] - mrun[cf]);
          sc[rf][cf][r] = p;
          ls[cf] += p;
        }
#pragma unroll
    for (int cf = 0; cf < 2; cf++) {
      float s2 = ls[cf];
      s2 += __shfl_xor(s2, 16);
      s2 += __shfl_xor(s2, 32);
      lrun[cf] += s2;
    }

    // pack P -> wave-private LDS [q][kv]
#pragma unroll
    for (int rf = 0; rf < 4; rf++)
#pragma unroll
      for (int cf = 0; cf < 2; cf++) {
        h4 p4;
#pragma unroll
        for (int r = 0; r < 4; r++) p4[r] = (_Float16)sc[rf][cf][r];
        *(h4*)&lP[w][(lq + 16 * cf) * 72 + rf * 16 + hi * 4] = p4;
      }
    asm volatile("s_waitcnt lgkmcnt(0)" ::: "memory");
    __builtin_amdgcn_sched_barrier(0);

    // O^T += V^T P^T. V from shared swizzled LDS.
    {
      const _Float16* vb = &lV[tk & 1][0];
#pragma unroll
      for (int kvc = 0; kvc < 2; kvc++) {
        h8 vf[4];
#pragma unroll
        for (int rf = 0; rf < 4; rf++)
          vf[rf] = *(const h8*)&vb[(rf * 16 + lq) * 64 + (((kvc * 4 + hi) ^ (lq & 7)) * 8)];
        h8 pb[2];
#pragma unroll
        for (int cf = 0; cf < 2; cf++)
          pb[cf] = *(const h8*)&lP[w][(lq + 16 * cf) * 72 + kvc * 32 + hi * 8];
#pragma unroll
        for (int rf = 0; rf < 4; rf++)
#pragma unroll
          for (int cf = 0; cf < 2; cf++)
            ot[rf][cf] = __builtin_amdgcn_mfma_f32_16x16x32_f16(vf[rf], pb[cf], ot[rf][cf], 0, 0, 0);
      }
    }
  }

  // normalize + store to AO[b*S+q][h*64+dv] f16
#pragma unroll
  for (int cf = 0; cf < 2; cf++) {
    float inv = 1.0f / lrun[cf];
    size_t row = (size_t)b * S_LEN + q0 + lq + 16 * cf;
#pragma unroll
    for (int rf = 0; rf < 4; rf++) {
      h4 o;
#pragma unroll
      for (int r = 0; r < 4; r++) o[r] = (_Float16)(ot[rf][cf][r] * inv);
      *(h4*)&AO[row * DMODEL + h * DH + rf * 16 + hi * 4] = o;
    }
  }
}

extern "C" void kernel_launch(void* const* d_in, const int* in_sizes, int n_in,
                              void* d_out, int out_size, void* d_ws, size_t ws_size,
                              hipStream_t stream) {
  const float* x  = (const float*)d_in[0];
  const float* Wq = (const float*)d_in[1];
  const float* Wk = (const float*)d_in[2];
  const float* Wv = (const float*)d_in[3];
  const float* Wo = (const float*)d_in[4];
  const float* tp = (const float*)d_in[5];

  float* y  = (float*)d_out;                 // 16,777,216 f32
  float* Ko = y + (size_t)16777216;          //  4,194,304 (post-RoPE K fp32)
  float* Vo = Ko + (size_t)4194304;          //  4,194,304 (V fp32)

  // workspace carve (fp16 elems) — total 68.5 MB. xh..woh adjacent => single cvt;
  // wqh/wkh/wvh adjacent => ONE fused QKV GEMM (N=3072).
  _Float16* xh  = (_Float16*)d_ws;           // 16,777,216
  _Float16* wqh = xh + 16777216;             //  4,194,304
  _Float16* wkh = wqh + 4194304;             //  1,048,576
  _Float16* wvh = wkh + 1048576;             //  1,048,576
  _Float16* woh = wvh + 1048576;             //  4,194,304
  _Float16* Kh  = woh + 4194304;             //  4,194,304  [b][g][s][64]
  _Float16* Vth = Kh + 4194304;              //  4,194,304  [b][g][64][s]
  float2*   rtab = (float2*)(Vth + 4194304); //    524,288 B
  _Float16* AOh = xh;                        // alias: x dead after QKV GEMM
  _Float16* Qh  = (_Float16*)d_out;          // alias: first 32MB of y; y written last
  (void)wkh; (void)wvh;

  cvt_all<<<2048, 256, 0, stream>>>(x, Wq, Wk, Wv, Wo, xh);
  rope_table_k<<<256, 256, 0, stream>>>(rtab);

  gemm256<1><<<dim3(12, 32), 512, 0, stream>>>(xh, wqh, Qh, Kh, Ko, Vth, Vo, nullptr, rtab, tp);
  attn_fwd<<<dim3(8, 256), 256, 0, stream>>>(Qh, Kh, Vth, AOh);
  gemm256<3><<<dim3(8, 32), 512, 0, stream>>>(AOh, woh, nullptr, nullptr, nullptr, nullptr, nullptr, y, rtab, tp);
}